// Round 3
// baseline (211.128 us; speedup 1.0000x reference)
//
#include <hip/hip_runtime.h>

// 2D CDF 5/3 lifting wavelet, fused, register-horizontal + single-barrier vertical.
// Input  x : (24, 1024, 1024) fp32. Output: (8, 12, 512, 512) fp32,
// planes ordered LL(0..2) LH(3..5) HL(6..8) HH(9..11).
//
// Per block: 32x32 half-res tile, 256 threads, ONE barrier.
// Phase A: each item loads a 24-float row window from global (float4),
//          computes horizontal d,s in registers, writes 8 s + 8 d via ds_write_b128.
// Phase B: each thread does vertical lifting for 1 row x 4 cols entirely in
//          registers (LH/HH recomputed 3x — VALU is idle, LDS/barriers are not),
//          then 4 coalesced float4 stores.

static __device__ __forceinline__ int mref(int k) {
    // _rpad reflect in half-res index space (N=512): e[-1]->E[1], e[512]->E[510]
    return k < 0 ? 1 : (k > 511 ? 510 : k);
}

static __device__ __forceinline__ float4 lift_h(float4 o, float4 a, float4 b) {
    return make_float4(o.x - 0.5f * (a.x + b.x),
                       o.y - 0.5f * (a.y + b.y),
                       o.z - 0.5f * (a.z + b.z),
                       o.w - 0.5f * (a.w + b.w));
}
static __device__ __forceinline__ float4 lift_l(float4 e, float4 a, float4 b) {
    return make_float4(e.x + 0.25f * (a.x + b.x),
                       e.y + 0.25f * (a.y + b.y),
                       e.z + 0.25f * (a.z + b.z),
                       e.w + 0.25f * (a.w + b.w));
}

__global__ __launch_bounds__(256, 6) void ilwt53_v3(const float* __restrict__ x,
                                                    float* __restrict__ out) {
    const int tid = threadIdx.x;
    const int c0  = blockIdx.x * 32;   // half-res col origin
    const int r0  = blockIdx.y * 32;   // half-res row origin
    const int img = blockIdx.z;        // b*3 + ch
    const int rb  = 2 * r0 - 4;        // full-res row base (4-row halo)

    // row stride 36: multiple of 4 (b128 alignment) + bank-phase offset per row
    __shared__ float sS[72 * 36];      // horizontal smooth, cols c0..c0+31
    __shared__ float sD[72 * 36];      // horizontal detail, cols c0..c0+31 (d[c..c+7] per group)

    const float* __restrict__ xim = x + (size_t)img * (1024 * 1024);

    // ---- Phase A: global -> registers (horizontal lifting) -> LDS ----
    // 72 rows x 4 col-groups = 288 items; item owns half-res cols c..c+7.
    #pragma unroll
    for (int it = 0; it < 2; ++it) {
        int i = tid + it * 256;
        if (i < 288) {
            int lr = i >> 2, g = i & 3;
            int gy = rb + lr; gy = gy < 0 ? 0 : (gy > 1023 ? 1023 : gy);
            const float* __restrict__ row = xim + (size_t)gy * 1024;
            int c  = c0 + 8 * g;       // first owned half-res col
            int fb = 2 * c - 4;        // 24-float full-res window base (16B aligned)

            float w[24];
            if (fb >= 0 && fb + 23 <= 1023) {
                const float4* p = (const float4*)(row + fb);
                #pragma unroll
                for (int q = 0; q < 6; ++q) {
                    float4 v = p[q];
                    w[4*q] = v.x; w[4*q+1] = v.y; w[4*q+2] = v.z; w[4*q+3] = v.w;
                }
            } else {
                #pragma unroll
                for (int q = 0; q < 24; ++q) {
                    int gx = fb + q; gx = gx < 0 ? 0 : (gx > 1023 ? 1023 : gx);
                    w[q] = row[gx];
                }
            }
            // window layout: E[c-2+u] = w[2u], O[c-2+u] = w[2u+1], u = 0..11
            // d[t] is global d[c-1+t], t = 0..9
            float d[10];
            #pragma unroll
            for (int t = 0; t < 10; ++t)
                d[t] = w[2*t+3] - 0.5f * (w[2*t] + w[2*t+4]);
            // horizontal image-edge fixes: d[0] = O[0]-E[1]; d[511] = O[511]-E[510]
            if (c == 0)   d[1] = w[5]  - w[6];    // global j=0  (t=1)
            if (c == 504) d[8] = w[19] - w[16];   // global j=511 (t=8)

            float s[8];
            #pragma unroll
            for (int i2 = 0; i2 < 8; ++i2)
                s[i2] = w[2*i2+4] + 0.25f * (d[i2] + d[i2+2]);
            // s edge fixes: s[0] = E[0] + 0.5*d[1]; s[511] = E[511] + 0.5*d[510]
            if (c == 0)   s[0] = w[4]  + 0.5f * d[2];
            if (c == 504) s[7] = w[18] + 0.5f * d[7];

            float4* ps = (float4*)(sS + lr * 36 + 8 * g);
            ps[0] = make_float4(s[0], s[1], s[2], s[3]);
            ps[1] = make_float4(s[4], s[5], s[6], s[7]);
            float4* pd = (float4*)(sD + lr * 36 + 8 * g);
            pd[0] = make_float4(d[1], d[2], d[3], d[4]);   // global d[c..c+3]
            pd[1] = make_float4(d[5], d[6], d[7], d[8]);   // global d[c+4..c+7]
        }
    }
    __syncthreads();

    // ---- Phase B: vertical lifting in registers, 1 row x 4 cols per thread ----
    {
        int rr = tid >> 3, ccg = tid & 7, co = 4 * ccg;
        int r  = r0 + rr;
        int km = mref(r - 1), kp = mref(r + 1);

        const float* sSc = sS + co;
        const float* sDc = sD + co;
        // half-res index k -> local full-res LDS row: even 2(k-r0)+4, odd 2(k-r0)+5
        auto SE = [&](int k) { return *(const float4*)(sSc + (2 * (k - r0) + 4) * 36); };
        auto SO = [&](int k) { return *(const float4*)(sSc + (2 * (k - r0) + 5) * 36); };
        auto DE = [&](int k) { return *(const float4*)(sDc + (2 * (k - r0) + 4) * 36); };
        auto DO = [&](int k) { return *(const float4*)(sDc + (2 * (k - r0) + 5) * 36); };
        auto LH = [&](int k) { return lift_h(SO(k), SE(mref(k - 1)), SE(mref(k + 1))); };
        auto HH = [&](int k) { return lift_h(DO(k), DE(mref(k - 1)), DE(mref(k + 1))); };

        float4 lhm = LH(km), lhc = LH(r), lhp = LH(kp);
        float4 ll  = lift_l(SE(r), lhm, lhp);
        float4 hhm = HH(km), hhc = HH(r), hhp = HH(kp);
        float4 hl  = lift_l(DE(r), hhm, hhp);

        const size_t plane = 512 * 512;
        float* __restrict__ ob = out + ((size_t)(img / 3) * 12 + (img % 3)) * plane;
        size_t o = (size_t)r * 512 + c0 + co;
        *(float4*)(ob + o)             = ll;
        *(float4*)(ob + o + 3 * plane) = lhc;
        *(float4*)(ob + o + 6 * plane) = hl;
        *(float4*)(ob + o + 9 * plane) = hhc;
    }
}

extern "C" void kernel_launch(void* const* d_in, const int* in_sizes, int n_in,
                              void* d_out, int out_size, void* d_ws, size_t ws_size,
                              hipStream_t stream) {
    const float* x = (const float*)d_in[0];
    float* out = (float*)d_out;
    dim3 grid(16, 16, 24);   // 16x16 half-res tiles per image, 24 images
    dim3 block(256);
    hipLaunchKernelGGL(ilwt53_v3, grid, block, 0, stream, x, out);
}

// Round 4
// 181.552 us; speedup vs baseline: 1.1629x; 1.1629x over previous
//
#include <hip/hip_runtime.h>

// 2D CDF 5/3 lifting wavelet — zero-LDS, zero-barrier columnar rolling kernel.
// Input  x : (24, 1024, 1024) fp32. Output: (8, 12, 512, 512) fp32,
// planes ordered LL(0..2) LH(3..5) HL(6..8) HH(9..11).
//
// Each thread owns 4 half-res columns and 16 half-res output rows, and rolls a
// vertical lifting pipeline entirely in registers:
//   per output row r: load full-res rows 2r+4, 2r+5 (4x float4 each),
//   horizontal-lift them in registers, advance LH/HH pipeline, 4 float4 stores.
// No LDS, no __syncthreads. MLP = 8 independent float4 loads per iteration.

static __device__ __forceinline__ int mref(int k) {
    // _rpad reflect in half-res index space (N=512): e[-1]->E[1], e[512]->E[510]
    return k < 0 ? 1 : (k > 511 ? 510 : k);
}

static __device__ __forceinline__ float4 f4_sub_half(float4 o, float4 a, float4 b) {
    // o - 0.5*(a+b)   (0.5*t is exact; fma contraction bit-matches 2-op form)
    return make_float4(o.x - 0.5f * (a.x + b.x), o.y - 0.5f * (a.y + b.y),
                       o.z - 0.5f * (a.z + b.z), o.w - 0.5f * (a.w + b.w));
}
static __device__ __forceinline__ float4 f4_add_q(float4 e, float4 a, float4 b) {
    // e + 0.25*(a+b)
    return make_float4(e.x + 0.25f * (a.x + b.x), e.y + 0.25f * (a.y + b.y),
                       e.z + 0.25f * (a.z + b.z), e.w + 0.25f * (a.w + b.w));
}

struct SD { float4 s, d; };

// Horizontal lifting of one full-res row for this thread's 4 half-res cols.
// fb = 2*c - 4 (16-float window base, 16B aligned). Window: E[c-2..c+5], O[c-2..c+5].
static __device__ __forceinline__ SD hrow(const float* __restrict__ xim, int y, int fb) {
    y = y < 0 ? 0 : (y > 1023 ? 1023 : y);
    const float* __restrict__ row = xim + (size_t)y * 1024;
    int fbc = fb < 0 ? 0 : (fb > 1008 ? 1008 : fb);

    float w[16];
    {
        const float4* p = (const float4*)(row + fbc);
        float4 v0 = p[0], v1 = p[1], v2 = p[2], v3 = p[3];
        w[0]=v0.x; w[1]=v0.y; w[2]=v0.z; w[3]=v0.w;
        w[4]=v1.x; w[5]=v1.y; w[6]=v1.z; w[7]=v1.w;
        w[8]=v2.x; w[9]=v2.y; w[10]=v2.z; w[11]=v2.w;
        w[12]=v3.x; w[13]=v3.y; w[14]=v3.z; w[15]=v3.w;
    }
    if (fb < 0) {            // c == 0: loaded from 0, logical base -4 -> shift right 4
        #pragma unroll
        for (int q = 15; q >= 4; --q) w[q] = w[q - 4];
    }
    if (fb > 1008) {         // c == 508: loaded from 1008, logical base 1012 -> shift left 4
        #pragma unroll
        for (int q = 0; q <= 11; ++q) w[q] = w[q + 4];
    }

    // w: E[c-2+u] = w[2u], O[c-2+u] = w[2u+1], u = 0..7
    // d[t] = detail at half-res col c-1+t, t = 0..5
    float d[6];
    #pragma unroll
    for (int t = 0; t < 6; ++t)
        d[t] = w[2*t + 3] - 0.5f * (w[2*t] + w[2*t + 4]);
    if (fb < 0)    d[1] = w[5]  - w[6];   // col 0:   O[0]  - E[1]
    if (fb > 1008) d[4] = w[11] - w[8];   // col 511: O[511]- E[510]

    float4 s;
    s.x = w[4]  + 0.25f * (d[0] + d[2]);
    s.y = w[6]  + 0.25f * (d[1] + d[3]);
    s.z = w[8]  + 0.25f * (d[2] + d[4]);
    s.w = w[10] + 0.25f * (d[3] + d[5]);
    if (fb < 0)    s.x = w[4]  + 0.5f * d[2];   // col 0:   E[0]  + 0.5*d[1]
    if (fb > 1008) s.w = w[10] + 0.5f * d[3];   // col 511: E[511]+ 0.5*d[510]

    SD r; r.s = s; r.d = make_float4(d[1], d[2], d[3], d[4]);
    return r;
}

__global__ __launch_bounds__(128) void ilwt53_v4(const float* __restrict__ x,
                                                 float* __restrict__ out) {
    const int c   = 4 * threadIdx.x;      // first owned half-res col (0..508)
    const int fb  = 2 * c - 4;            // full-res window base
    const int R   = 16 * blockIdx.x;      // first owned half-res row
    const int img = blockIdx.y;           // b*3 + ch

    const float* __restrict__ xim = x + (size_t)img * (1024 * 1024);
    const size_t plane = 512 * 512;
    float* __restrict__ ob = out + ((size_t)(img / 3) * 12 + (img % 3)) * plane + c;

    // ---- Prologue: build pipeline state for row R (mref-mapped, generic) ----
    // SE(k)/DE(k) <- full-res row 2*mref(k); SO(k)/DO(k) <- row 2*mref(k)+1
    float4 sEa, dEa, sEb, dEb, sOc, dOc, lhm, hhm, lh0, hh0;
    {
        SD a  = hrow(xim, 2 * R, fb);                 sEa = a.s;  dEa = a.d;   // SE(R)
        SD b  = hrow(xim, 2 * (R + 1), fb);           sEb = b.s;  dEb = b.d;   // SE(R+1)
        SD oc = hrow(xim, 2 * (R + 1) + 1, fb);       sOc = oc.s; dOc = oc.d;  // SO(R+1)
        SD o0 = hrow(xim, 2 * R + 1, fb);                                      // SO(R)
        SD em = hrow(xim, 2 * mref(R - 1), fb);                                // SE(mref(R-1))
        lh0 = f4_sub_half(o0.s, em.s, sEb);    // LH(R)
        hh0 = f4_sub_half(o0.d, em.d, dEb);
        int kA = mref(R - 1);
        SD oA  = hrow(xim, 2 * kA + 1, fb);                                    // SO(kA)
        SD eAm = hrow(xim, 2 * mref(kA - 1), fb);
        SD eAp = hrow(xim, 2 * mref(kA + 1), fb);
        lhm = f4_sub_half(oA.s, eAm.s, eAp.s); // LH(mref(R-1))
        hhm = f4_sub_half(oA.d, eAm.d, eAp.d);
    }

    // ---- Hot loop: emit rows R .. R+15 ----
    #pragma unroll 8
    for (int r = R; r < R + 16; ++r) {
        SD e2 = hrow(xim, 2 * r + 4, fb);    // SE(r+2) source (clamped past bottom)
        SD o2 = hrow(xim, 2 * r + 5, fb);    // SO(r+2) source

        float4 sE2 = e2.s, dE2 = e2.d;
        if (r == 510) { sE2 = sEa; dE2 = dEa; }      // SE(mref(512)) = SE(510)

        float4 lh1 = f4_sub_half(sOc, sEa, sE2);     // LH(r+1)
        float4 hh1 = f4_sub_half(dOc, dEa, dE2);
        if (r == 511) { lh1 = lhm; hh1 = hhm; }      // LH(mref(512)) = LH(510)

        float4 LL = f4_add_q(sEa, lhm, lh1);
        float4 HL = f4_add_q(dEa, hhm, hh1);

        size_t o = (size_t)r * 512;
        *(float4*)(ob + o)             = LL;
        *(float4*)(ob + o + 3 * plane) = lh0;
        *(float4*)(ob + o + 6 * plane) = HL;
        *(float4*)(ob + o + 9 * plane) = hh0;

        lhm = lh0; lh0 = lh1; hhm = hh0; hh0 = hh1;
        sEa = sEb; dEa = dEb; sEb = e2.s; dEb = e2.d;
        sOc = o2.s; dOc = o2.d;
    }
}

extern "C" void kernel_launch(void* const* d_in, const int* in_sizes, int n_in,
                              void* d_out, int out_size, void* d_ws, size_t ws_size,
                              hipStream_t stream) {
    const float* x = (const float*)d_in[0];
    float* out = (float*)d_out;
    dim3 grid(32, 24);    // 32 row-chunks (16 rows each) x 24 images = 768 blocks
    dim3 block(128);      // 128 threads = 128 col-groups (4 half-res cols each)
    hipLaunchKernelGGL(ilwt53_v4, grid, block, 0, stream, x, out);
}